// Round 6
// baseline (188.009 us; speedup 1.0000x reference)
//
#include <hip/hip_runtime.h>
#include <math.h>

#define NN 50000
#define NE 800000
#define DD 64

typedef __attribute__((ext_vector_type(8))) short short8v;
typedef __attribute__((ext_vector_type(4))) float floatx4;

__device__ __forceinline__ unsigned bf16r(float x) {  // round-to-nearest-even bf16
  unsigned u = __float_as_uint(x);
  return (u + 0x7fffu + ((u >> 16) & 1u)) >> 16;
}

// -------------------- kernels --------------------

// zero deg[] ourselves: hipMemsetAsync's fillBuffer kernel costs ~40us (R5 profile)
__global__ void k_zero(int4* __restrict__ p, int n4) {
  int i = blockIdx.x * 256 + threadIdx.x;
  if (i < n4) p[i] = make_int4(0, 0, 0, 0);
}

// histogram dst degrees, capturing per-edge position (atomic-with-return)
__global__ void k_hist(const int* __restrict__ dst, int* __restrict__ deg,
                       int* __restrict__ pos) {
  int e = blockIdx.x * 256 + threadIdx.x;
  if (e < NE) pos[e] = atomicAdd(&deg[dst[e]], 1);
}

__global__ void k_scan1(const int* __restrict__ deg, int* __restrict__ rp,
                        int* __restrict__ bsum) {
  __shared__ int tmp[1024];
  int t = threadIdx.x;
  int i = blockIdx.x * 1024 + t;
  int v = (i < NN) ? deg[i] : 0;
  tmp[t] = v;
  __syncthreads();
  for (int off = 1; off < 1024; off <<= 1) {
    int x = (t >= off) ? tmp[t - off] : 0;
    __syncthreads();
    tmp[t] += x;
    __syncthreads();
  }
  if (i < NN) rp[i] = tmp[t] - v;  // exclusive within block
  if (t == 1023) bsum[blockIdx.x] = tmp[1023];
}

// exclusive scan of <=64 block sums with one wave
__global__ void k_scan2(int* __restrict__ bsum, int nb) {
  int t = threadIdx.x;
  int orig = (t < nb) ? bsum[t] : 0;
  int v = orig;
#pragma unroll
  for (int off = 1; off < 64; off <<= 1) {
    int x = __shfl_up(v, off, 64);
    if (t >= off) v += x;
  }
  if (t < nb) bsum[t] = v - orig;
}

__global__ void k_scan3(int* __restrict__ rp, const int* __restrict__ bsum) {
  int i = blockIdx.x * 1024 + threadIdx.x;
  if (i < NN) rp[i] += bsum[blockIdx.x];
  if (i == 0) rp[NN] = NE;
}

// atomic-free scatter, 4 edges/thread with vector loads
__global__ void k_scatter(const int4* __restrict__ src4, const int4* __restrict__ dst4,
                          const int* __restrict__ rp, const int4* __restrict__ pos4,
                          int* __restrict__ ssrc) {
  int q = blockIdx.x * 256 + threadIdx.x;  // NE/4 = 200000 quads
  if (q >= NE / 4) return;
  int4 s = src4[q], dn = dst4[q], p = pos4[q];
  ssrc[rp[dn.x] + p.x] = s.x;
  ssrc[rp[dn.y] + p.y] = s.y;
  ssrc[rp[dn.z] + p.z] = s.z;
  ssrc[rp[dn.w] + p.w] = s.w;
}

// MFMA FC: hfb[n*64+d] = pack(bf16(h[row(n)][d]), bf16(relu(h[row(n)] @ W^T + b)[d]))
// row(n) = ids ? ids[n] : n. One wave per 16-node strip, no LDS.
// 16x16x32 frag layout: A row = lane&15, k = (lane>>4)*8 + i
//                       B col = lane&15, k = (lane>>4)*8 + i
//                       D col = lane&15, row = (lane>>4)*4 + reg
__global__ void __launch_bounds__(256) k_fc_mfma(const float* __restrict__ h,
                                                 const int* __restrict__ ids,
                                                 const float* __restrict__ W,
                                                 const float* __restrict__ b,
                                                 unsigned* __restrict__ hfb) {
  int lane = threadIdx.x & 63;
  int wid = threadIdx.x >> 6;
  int nbase = blockIdx.x * 64 + wid * 16;
  if (nbase >= NN) return;  // 50000 = 3125*16, strips exact
  int r16 = lane & 15, kg = lane >> 4;

  int rowA = ids ? ids[nbase + r16] : (nbase + r16);
  const float* hrow = h + (size_t)rowA * DD;
  short8v afr[2];
#pragma unroll
  for (int kt = 0; kt < 2; ++kt) {
    int k0 = kt * 32 + kg * 8;
#pragma unroll
    for (int i = 0; i < 8; ++i) afr[kt][i] = (short)bf16r(hrow[k0 + i]);
  }
  // epilogue row indices for this lane's 4 output rows
  int orow[4];
#pragma unroll
  for (int r = 0; r < 4; ++r) {
    int node = nbase + kg * 4 + r;
    orow[r] = ids ? ids[node] : node;
  }
  // B fragments (4 d-tiles x 2 k-tiles); W identical across waves -> L2-hot
  short8v bfr[4][2];
#pragma unroll
  for (int dt = 0; dt < 4; ++dt) {
    const float* wrow = W + (dt * 16 + r16) * 64;
#pragma unroll
    for (int kt = 0; kt < 2; ++kt) {
      int k0 = kt * 32 + kg * 8;
#pragma unroll
      for (int i = 0; i < 8; ++i) bfr[dt][kt][i] = (short)bf16r(wrow[k0 + i]);
    }
  }
#pragma unroll
  for (int dt = 0; dt < 4; ++dt) {
    floatx4 acc = {0.f, 0.f, 0.f, 0.f};
    acc = __builtin_amdgcn_mfma_f32_16x16x32_bf16(afr[0], bfr[dt][0], acc, 0, 0, 0);
    acc = __builtin_amdgcn_mfma_f32_16x16x32_bf16(afr[1], bfr[dt][1], acc, 0, 0, 0);
    int d = dt * 16 + r16;
    float bias = b[d];
#pragma unroll
    for (int r = 0; r < 4; ++r) {
      int node = nbase + kg * 4 + r;
      float feat = fmaxf(acc[r] + bias, 0.f);
      float hv = h[(size_t)orow[r] * DD + d];
      hfb[node * DD + d] = bf16r(hv) | (bf16r(feat) << 16);
    }
  }
}

// One wave per dst node. |e| bounded -> softmax without max-subtraction.
// bf16-packed gather: one u32 per lane per edge. 8 independent partials.
__global__ void __launch_bounds__(256) k_edge(const unsigned* __restrict__ hfb,
                                              const float* __restrict__ h,
                                              const int* __restrict__ ids,
                                              const int* __restrict__ rp,
                                              const int* __restrict__ ssrc,
                                              float* __restrict__ hout, int ostride) {
  int d = threadIdx.x & 63;
  int node = blockIdx.x * 4 + (threadIdx.x >> 6);
  if (node >= NN) return;
  int beg = rp[node], end = rp[node + 1];
  int hrow = ids ? ids[node] : node;
  float hd = h[(size_t)hrow * DD + d];
  float s0 = 0.f, s1 = 0.f, s2 = 0.f, s3 = 0.f;
  float s4 = 0.f, s5 = 0.f, s6 = 0.f, s7 = 0.f;
  float a0 = 0.f, a1 = 0.f, a2 = 0.f, a3 = 0.f;
  float a4 = 0.f, a5 = 0.f, a6 = 0.f, a7 = 0.f;
  int p = beg;
#define EDGE_STEP(j, sj, aj)                                        \
  {                                                                 \
    unsigned v = hfb[ssrc[p + j] * DD + d];                         \
    float hv = __uint_as_float(v << 16);                            \
    float fv = __uint_as_float(v & 0xffff0000u);                    \
    float ex = __expf(hv * hd);                                     \
    sj += ex;                                                       \
    aj = fmaf(fv, ex, aj);                                          \
  }
  for (; p + 8 <= end; p += 8) {
    EDGE_STEP(0, s0, a0) EDGE_STEP(1, s1, a1) EDGE_STEP(2, s2, a2) EDGE_STEP(3, s3, a3)
    EDGE_STEP(4, s4, a4) EDGE_STEP(5, s5, a5) EDGE_STEP(6, s6, a6) EDGE_STEP(7, s7, a7)
  }
  for (; p < end; ++p) EDGE_STEP(0, s0, a0)
#undef EDGE_STEP
  float s = ((s0 + s1) + (s2 + s3)) + ((s4 + s5) + (s6 + s7));
  float a = ((a0 + a1) + (a2 + a3)) + ((a4 + a5) + (a6 + a7));
  hout[node * ostride + d] = (end > beg) ? a / s : 0.f;
}

// out[0:64] = emb[ids[n]]; out[64:128] = norm(h1); out[128:192] normalized in place
__global__ void __launch_bounds__(256) k_final(const float* __restrict__ emb,
                                               const int* __restrict__ ids,
                                               const float* __restrict__ h1,
                                               float* __restrict__ out) {
  int d = threadIdx.x & 63;
  int node = blockIdx.x * 4 + (threadIdx.x >> 6);
  if (node >= NN) return;
  float v1 = h1[node * DD + d], v2 = out[node * 192 + 128 + d];
  float s1 = v1 * v1, s2 = v2 * v2;
#pragma unroll
  for (int off = 32; off > 0; off >>= 1) {
    s1 += __shfl_xor(s1, off, 64);
    s2 += __shfl_xor(s2, off, 64);
  }
  out[node * 192 + d] = emb[(size_t)ids[node] * DD + d];
  out[node * 192 + 64 + d] = v1 / fmaxf(sqrtf(s1), 1e-12f);
  out[node * 192 + 128 + d] = v2 / fmaxf(sqrtf(s2), 1e-12f);
}

// -------------------- launch --------------------

extern "C" void kernel_launch(void* const* d_in, const int* in_sizes, int n_in,
                              void* d_out, int out_size, void* d_ws, size_t ws_size,
                              hipStream_t stream) {
  const int* node_ids = (const int*)d_in[0];
  const int* src = (const int*)d_in[1];
  const int* dst = (const int*)d_in[2];
  const float* emb = (const float*)d_in[3];
  const float* W0 = (const float*)d_in[4];
  const float* b0 = (const float*)d_in[5];
  const float* W1 = (const float*)d_in[8];
  const float* b1 = (const float*)d_in[9];
  float* out = (float*)d_out;

  size_t o = 0;
  auto alloc = [&](size_t nbytes) {
    char* p = (char*)d_ws + o;
    o += (nbytes + 255) & ~(size_t)255;
    return (void*)p;
  };
  float* h1 = (float*)alloc((size_t)NN * DD * 4);
  unsigned* hfb = (unsigned*)alloc((size_t)NN * DD * 4);
  int* deg = (int*)alloc((size_t)(NN + 12) * 4);  // padded to int4 multiple
  int* rp = (int*)alloc((size_t)(NN + 1) * 4);
  int* bsum = (int*)alloc(64 * 4);
  int* ssrc = (int*)alloc((size_t)NE * 4);
  int* pos = (int*)alloc((size_t)NE * 4);
  (void)o; (void)ws_size; (void)in_sizes; (void)n_in; (void)out_size;

  int n4 = (NN + 3) / 4;  // 12500 int4s
  k_zero<<<(n4 + 255) / 256, 256, 0, stream>>>((int4*)deg, n4);
  k_hist<<<(NE + 255) / 256, 256, 0, stream>>>(dst, deg, pos);
  int NB = (NN + 1023) / 1024;
  k_scan1<<<NB, 1024, 0, stream>>>(deg, rp, bsum);
  k_scan2<<<1, 64, 0, stream>>>(bsum, NB);
  k_scan3<<<NB, 1024, 0, stream>>>(rp, bsum);
  k_scatter<<<(NE / 4 + 255) / 256, 256, 0, stream>>>(
      (const int4*)src, (const int4*)dst, rp, (const int4*)pos, ssrc);

  // layer 1: h0 = emb[ids[.]] read in place via indirection
  k_fc_mfma<<<(NN + 63) / 64, 256, 0, stream>>>(emb, node_ids, W0, b0, hfb);
  k_edge<<<(NN + 3) / 4, 256, 0, stream>>>(hfb, emb, node_ids, rp, ssrc, h1, DD);
  // layer 2
  k_fc_mfma<<<(NN + 63) / 64, 256, 0, stream>>>(h1, nullptr, W1, b1, hfb);
  k_edge<<<(NN + 3) / 4, 256, 0, stream>>>(hfb, h1, nullptr, rp, ssrc, out + 128, 192);

  k_final<<<(NN + 3) / 4, 256, 0, stream>>>(emb, node_ids, h1, out);
}

// Round 7
// 177.645 us; speedup vs baseline: 1.0583x; 1.0583x over previous
//
#include <hip/hip_runtime.h>
#include <math.h>

#define NN 50000
#define NE 800000
#define DD 64

typedef __attribute__((ext_vector_type(8))) short short8v;
typedef __attribute__((ext_vector_type(4))) float floatx4;

__device__ __forceinline__ unsigned bf16r(float x) {  // round-to-nearest-even bf16
  unsigned u = __float_as_uint(x);
  return (u + 0x7fffu + ((u >> 16) & 1u)) >> 16;
}

// -------------------- kernels --------------------

// zero deg[] ourselves (runtime fillBuffer for small memset costs ~40us launch-bound)
__global__ void k_zero(int4* __restrict__ p, int n4) {
  int i = blockIdx.x * 256 + threadIdx.x;
  if (i < n4) p[i] = make_int4(0, 0, 0, 0);
}

// histogram dst degrees, 4 edges/thread, capturing per-edge position
__global__ void k_hist(const int4* __restrict__ dst4, int* __restrict__ deg,
                       int4* __restrict__ pos4) {
  int q = blockIdx.x * 256 + threadIdx.x;  // NE/4 quads
  if (q >= NE / 4) return;
  int4 dn = dst4[q];
  int4 p;
  p.x = atomicAdd(&deg[dn.x], 1);
  p.y = atomicAdd(&deg[dn.y], 1);
  p.z = atomicAdd(&deg[dn.z], 1);
  p.w = atomicAdd(&deg[dn.w], 1);
  pos4[q] = p;
}

__global__ void k_scan1(const int* __restrict__ deg, int* __restrict__ rp,
                        int* __restrict__ bsum) {
  __shared__ int tmp[1024];
  int t = threadIdx.x;
  int i = blockIdx.x * 1024 + t;
  int v = (i < NN) ? deg[i] : 0;
  tmp[t] = v;
  __syncthreads();
  for (int off = 1; off < 1024; off <<= 1) {
    int x = (t >= off) ? tmp[t - off] : 0;
    __syncthreads();
    tmp[t] += x;
    __syncthreads();
  }
  if (i < NN) rp[i] = tmp[t] - v;  // exclusive within block
  if (t == 1023) bsum[blockIdx.x] = tmp[1023];
}

// exclusive scan of <=64 block sums with one wave
__global__ void k_scan2(int* __restrict__ bsum, int nb) {
  int t = threadIdx.x;
  int orig = (t < nb) ? bsum[t] : 0;
  int v = orig;
#pragma unroll
  for (int off = 1; off < 64; off <<= 1) {
    int x = __shfl_up(v, off, 64);
    if (t >= off) v += x;
  }
  if (t < nb) bsum[t] = v - orig;
}

__global__ void k_scan3(int* __restrict__ rp, const int* __restrict__ bsum) {
  int i = blockIdx.x * 1024 + threadIdx.x;
  if (i < NN) rp[i] += bsum[blockIdx.x];
  if (i == 0) rp[NN] = NE;
}

// atomic-free scatter, 4 edges/thread with vector loads
__global__ void k_scatter(const int4* __restrict__ src4, const int4* __restrict__ dst4,
                          const int* __restrict__ rp, const int4* __restrict__ pos4,
                          int* __restrict__ ssrc) {
  int q = blockIdx.x * 256 + threadIdx.x;
  if (q >= NE / 4) return;
  int4 s = src4[q], dn = dst4[q], p = pos4[q];
  ssrc[rp[dn.x] + p.x] = s.x;
  ssrc[rp[dn.y] + p.y] = s.y;
  ssrc[rp[dn.z] + p.z] = s.z;
  ssrc[rp[dn.w] + p.w] = s.w;
}

// MFMA FC: hfb[n*64+d] = pack(bf16(h[row(n)][d]), bf16(relu(h[row(n)] @ W^T + b)[d]))
// row(n) = ids ? ids[n] : n. One wave per 16-node strip, no LDS.
__global__ void __launch_bounds__(256) k_fc_mfma(const float* __restrict__ h,
                                                 const int* __restrict__ ids,
                                                 const float* __restrict__ W,
                                                 const float* __restrict__ b,
                                                 unsigned* __restrict__ hfb) {
  int lane = threadIdx.x & 63;
  int wid = threadIdx.x >> 6;
  int nbase = blockIdx.x * 64 + wid * 16;
  if (nbase >= NN) return;  // 50000 = 3125*16, strips exact
  int r16 = lane & 15, kg = lane >> 4;

  int rowA = ids ? ids[nbase + r16] : (nbase + r16);
  const float* hrow = h + (size_t)rowA * DD;
  short8v afr[2];
#pragma unroll
  for (int kt = 0; kt < 2; ++kt) {
    int k0 = kt * 32 + kg * 8;
#pragma unroll
    for (int i = 0; i < 8; ++i) afr[kt][i] = (short)bf16r(hrow[k0 + i]);
  }
  int orow[4];
#pragma unroll
  for (int r = 0; r < 4; ++r) {
    int node = nbase + kg * 4 + r;
    orow[r] = ids ? ids[node] : node;
  }
  short8v bfr[4][2];
#pragma unroll
  for (int dt = 0; dt < 4; ++dt) {
    const float* wrow = W + (dt * 16 + r16) * 64;
#pragma unroll
    for (int kt = 0; kt < 2; ++kt) {
      int k0 = kt * 32 + kg * 8;
#pragma unroll
      for (int i = 0; i < 8; ++i) bfr[dt][kt][i] = (short)bf16r(wrow[k0 + i]);
    }
  }
#pragma unroll
  for (int dt = 0; dt < 4; ++dt) {
    floatx4 acc = {0.f, 0.f, 0.f, 0.f};
    acc = __builtin_amdgcn_mfma_f32_16x16x32_bf16(afr[0], bfr[dt][0], acc, 0, 0, 0);
    acc = __builtin_amdgcn_mfma_f32_16x16x32_bf16(afr[1], bfr[dt][1], acc, 0, 0, 0);
    int d = dt * 16 + r16;
    float bias = b[d];
#pragma unroll
    for (int r = 0; r < 4; ++r) {
      int node = nbase + kg * 4 + r;
      float feat = fmaxf(acc[r] + bias, 0.f);
      float hv = h[(size_t)orow[r] * DD + d];
      hfb[node * DD + d] = bf16r(hv) | (bf16r(feat) << 16);
    }
  }
}

// One wave per dst node. Softmax without max-subtraction (|e| bounded).
// Predicated 8-wide batches: all 8 gathers issued before any exp -> full MLP
// even for the (dominant) deg<16 nodes; masked slots contribute ex=0.
__global__ void __launch_bounds__(256) k_edge(const unsigned* __restrict__ hfb,
                                              const float* __restrict__ h,
                                              const int* __restrict__ ids,
                                              const int* __restrict__ rp,
                                              const int* __restrict__ ssrc,
                                              float* __restrict__ hout, int ostride) {
  int d = threadIdx.x & 63;
  int node = blockIdx.x * 4 + (threadIdx.x >> 6);
  if (node >= NN) return;
  int beg = rp[node], end = rp[node + 1];
  int hrow = ids ? ids[node] : node;
  float hd = h[(size_t)hrow * DD + d];
  float s[8] = {0.f, 0.f, 0.f, 0.f, 0.f, 0.f, 0.f, 0.f};
  float a[8] = {0.f, 0.f, 0.f, 0.f, 0.f, 0.f, 0.f, 0.f};
  int lim = end - 1;
  for (int p = beg; p < end; p += 8) {
    unsigned v[8];
#pragma unroll
    for (int j = 0; j < 8; ++j) {
      int q = p + j;
      q = (q > lim) ? lim : q;            // clamp -> always-valid load
      v[j] = hfb[ssrc[q] * DD + d];
    }
#pragma unroll
    for (int j = 0; j < 8; ++j) {
      float hv = __uint_as_float(v[j] << 16);
      float fv = __uint_as_float(v[j] & 0xffff0000u);
      float ex = (p + j < end) ? __expf(hv * hd) : 0.f;
      s[j] += ex;
      a[j] = fmaf(fv, ex, a[j]);
    }
  }
  float ss = ((s[0] + s[1]) + (s[2] + s[3])) + ((s[4] + s[5]) + (s[6] + s[7]));
  float aa = ((a[0] + a[1]) + (a[2] + a[3])) + ((a[4] + a[5]) + (a[6] + a[7]));
  hout[node * ostride + d] = (end > beg) ? aa / ss : 0.f;
}

// out[0:64] = emb[ids[n]]; out[64:128] = norm(h1); out[128:192] normalized in place
__global__ void __launch_bounds__(256) k_final(const float* __restrict__ emb,
                                               const int* __restrict__ ids,
                                               const float* __restrict__ h1,
                                               float* __restrict__ out) {
  int d = threadIdx.x & 63;
  int node = blockIdx.x * 4 + (threadIdx.x >> 6);
  if (node >= NN) return;
  float v1 = h1[node * DD + d], v2 = out[node * 192 + 128 + d];
  float s1 = v1 * v1, s2 = v2 * v2;
#pragma unroll
  for (int off = 32; off > 0; off >>= 1) {
    s1 += __shfl_xor(s1, off, 64);
    s2 += __shfl_xor(s2, off, 64);
  }
  out[node * 192 + d] = emb[(size_t)ids[node] * DD + d];
  out[node * 192 + 64 + d] = v1 / fmaxf(sqrtf(s1), 1e-12f);
  out[node * 192 + 128 + d] = v2 / fmaxf(sqrtf(s2), 1e-12f);
}

// -------------------- launch --------------------

extern "C" void kernel_launch(void* const* d_in, const int* in_sizes, int n_in,
                              void* d_out, int out_size, void* d_ws, size_t ws_size,
                              hipStream_t stream) {
  const int* node_ids = (const int*)d_in[0];
  const int* src = (const int*)d_in[1];
  const int* dst = (const int*)d_in[2];
  const float* emb = (const float*)d_in[3];
  const float* W0 = (const float*)d_in[4];
  const float* b0 = (const float*)d_in[5];
  const float* W1 = (const float*)d_in[8];
  const float* b1 = (const float*)d_in[9];
  float* out = (float*)d_out;

  size_t o = 0;
  auto alloc = [&](size_t nbytes) {
    char* p = (char*)d_ws + o;
    o += (nbytes + 255) & ~(size_t)255;
    return (void*)p;
  };
  float* h1 = (float*)alloc((size_t)NN * DD * 4);
  unsigned* hfb = (unsigned*)alloc((size_t)NN * DD * 4);
  int* deg = (int*)alloc((size_t)(NN + 12) * 4);  // padded to int4 multiple
  int* rp = (int*)alloc((size_t)(NN + 1) * 4);
  int* bsum = (int*)alloc(64 * 4);
  int* ssrc = (int*)alloc((size_t)NE * 4);
  int* pos = (int*)alloc((size_t)NE * 4);
  (void)o; (void)ws_size; (void)in_sizes; (void)n_in; (void)out_size;

  int n4 = (NN + 3) / 4;
  k_zero<<<(n4 + 255) / 256, 256, 0, stream>>>((int4*)deg, n4);
  k_hist<<<(NE / 4 + 255) / 256, 256, 0, stream>>>((const int4*)dst, deg, (int4*)pos);
  int NB = (NN + 1023) / 1024;
  k_scan1<<<NB, 1024, 0, stream>>>(deg, rp, bsum);
  k_scan2<<<1, 64, 0, stream>>>(bsum, NB);
  k_scan3<<<NB, 1024, 0, stream>>>(rp, bsum);
  k_scatter<<<(NE / 4 + 255) / 256, 256, 0, stream>>>(
      (const int4*)src, (const int4*)dst, rp, (const int4*)pos, ssrc);

  // layer 1: h0 = emb[ids[.]] read in place via indirection
  k_fc_mfma<<<(NN + 63) / 64, 256, 0, stream>>>(emb, node_ids, W0, b0, hfb);
  k_edge<<<(NN + 3) / 4, 256, 0, stream>>>(hfb, emb, node_ids, rp, ssrc, h1, DD);
  // layer 2
  k_fc_mfma<<<(NN + 63) / 64, 256, 0, stream>>>(h1, nullptr, W1, b1, hfb);
  k_edge<<<(NN + 3) / 4, 256, 0, stream>>>(hfb, h1, nullptr, rp, ssrc, out + 128, 192);

  k_final<<<(NN + 3) / 4, 256, 0, stream>>>(emb, node_ids, h1, out);
}

// Round 8
// 172.283 us; speedup vs baseline: 1.0913x; 1.0311x over previous
//
#include <hip/hip_runtime.h>
#include <math.h>

#define NN 50000
#define NE 800000
#define DD 64
#define FC_BLOCKS 782  // ceil(NN/64)
#define N4 12500       // NN/4 ints of deg, zeroed as int4
#define ZB 49          // ceil(N4/256) zero blocks appended to fc1 grid

typedef __attribute__((ext_vector_type(8))) short short8v;
typedef __attribute__((ext_vector_type(4))) float floatx4;

__device__ __forceinline__ unsigned bf16r(float x) {  // round-to-nearest-even bf16
  unsigned u = __float_as_uint(x);
  return (u + 0x7fffu + ((u >> 16) & 1u)) >> 16;
}

// -------------------- kernels --------------------

// histogram dst degrees, 4 edges/thread, capturing per-edge position
__global__ void k_hist(const int4* __restrict__ dst4, int* __restrict__ deg,
                       int4* __restrict__ pos4) {
  int q = blockIdx.x * 256 + threadIdx.x;
  if (q >= NE / 4) return;
  int4 dn = dst4[q];
  int4 p;
  p.x = atomicAdd(&deg[dn.x], 1);
  p.y = atomicAdd(&deg[dn.y], 1);
  p.z = atomicAdd(&deg[dn.z], 1);
  p.w = atomicAdd(&deg[dn.w], 1);
  pos4[q] = p;
}

// block-level exclusive scan (1024 threads): shuffle scan per wave + cross-wave LDS
__global__ void k_scan1(const int* __restrict__ deg, int* __restrict__ rp,
                        int* __restrict__ bsum) {
  __shared__ int woff[16];
  int t = threadIdx.x;
  int i = blockIdx.x * 1024 + t;
  int v = (i < NN) ? deg[i] : 0;
  int lane = t & 63, w = t >> 6;
  int sc = v;  // inclusive scan within wave
#pragma unroll
  for (int off = 1; off < 64; off <<= 1) {
    int x = __shfl_up(sc, off, 64);
    if (lane >= off) sc += x;
  }
  if (lane == 63) woff[w] = sc;
  __syncthreads();
  if (t < 16) {
    int ws = woff[t];
    int s2 = ws;
#pragma unroll
    for (int off = 1; off < 16; off <<= 1) {
      int x = __shfl_up(s2, off, 64);
      if (t >= off) s2 += x;
    }
    woff[t] = s2 - ws;  // exclusive wave offset
    if (t == 15) bsum[blockIdx.x] = s2;  // block total
  }
  __syncthreads();
  if (i < NN) rp[i] = sc - v + woff[w];
}

// add cross-block offset: each block reduces bsum[0..blockIdx) with one wave
__global__ void k_scan3(int* __restrict__ rp, const int* __restrict__ bsum) {
  __shared__ int soff;
  if (threadIdx.x < 64) {
    int v = ((int)threadIdx.x < (int)blockIdx.x) ? bsum[threadIdx.x] : 0;
#pragma unroll
    for (int off = 32; off > 0; off >>= 1) v += __shfl_xor(v, off, 64);
    if (threadIdx.x == 0) soff = v;
  }
  __syncthreads();
  int i = blockIdx.x * 1024 + threadIdx.x;
  if (i < NN) rp[i] += soff;
  if (i == 0) rp[NN] = NE;
}

// atomic-free scatter, 4 edges/thread
__global__ void k_scatter(const int4* __restrict__ src4, const int4* __restrict__ dst4,
                          const int* __restrict__ rp, const int4* __restrict__ pos4,
                          int* __restrict__ ssrc) {
  int q = blockIdx.x * 256 + threadIdx.x;
  if (q >= NE / 4) return;
  int4 s = src4[q], dn = dst4[q], p = pos4[q];
  ssrc[rp[dn.x] + p.x] = s.x;
  ssrc[rp[dn.y] + p.y] = s.y;
  ssrc[rp[dn.z] + p.z] = s.z;
  ssrc[rp[dn.w] + p.w] = s.w;
}

// MFMA FC (+ optional deg-zero blocks appended to the grid for layer 1)
__global__ void __launch_bounds__(256) k_fc_mfma(const float* __restrict__ h,
                                                 const int* __restrict__ ids,
                                                 const float* __restrict__ W,
                                                 const float* __restrict__ b,
                                                 unsigned* __restrict__ hfb,
                                                 int4* __restrict__ zbuf, int n4) {
  if (blockIdx.x >= FC_BLOCKS) {  // zero-deg tail blocks (layer 1 only)
    int i = (blockIdx.x - FC_BLOCKS) * 256 + threadIdx.x;
    if (i < n4) zbuf[i] = make_int4(0, 0, 0, 0);
    return;
  }
  int lane = threadIdx.x & 63;
  int wid = threadIdx.x >> 6;
  int nbase = blockIdx.x * 64 + wid * 16;
  if (nbase >= NN) return;
  int r16 = lane & 15, kg = lane >> 4;

  int rowA = ids ? ids[nbase + r16] : (nbase + r16);
  const float* hrow = h + (size_t)rowA * DD;
  short8v afr[2];
#pragma unroll
  for (int kt = 0; kt < 2; ++kt) {
    int k0 = kt * 32 + kg * 8;
#pragma unroll
    for (int i = 0; i < 8; ++i) afr[kt][i] = (short)bf16r(hrow[k0 + i]);
  }
  int orow[4];
#pragma unroll
  for (int r = 0; r < 4; ++r) {
    int node = nbase + kg * 4 + r;
    orow[r] = ids ? ids[node] : node;
  }
  short8v bfr[4][2];
#pragma unroll
  for (int dt = 0; dt < 4; ++dt) {
    const float* wrow = W + (dt * 16 + r16) * 64;
#pragma unroll
    for (int kt = 0; kt < 2; ++kt) {
      int k0 = kt * 32 + kg * 8;
#pragma unroll
      for (int i = 0; i < 8; ++i) bfr[dt][kt][i] = (short)bf16r(wrow[k0 + i]);
    }
  }
#pragma unroll
  for (int dt = 0; dt < 4; ++dt) {
    floatx4 acc = {0.f, 0.f, 0.f, 0.f};
    acc = __builtin_amdgcn_mfma_f32_16x16x32_bf16(afr[0], bfr[dt][0], acc, 0, 0, 0);
    acc = __builtin_amdgcn_mfma_f32_16x16x32_bf16(afr[1], bfr[dt][1], acc, 0, 0, 0);
    int d = dt * 16 + r16;
    float bias = b[d];
#pragma unroll
    for (int r = 0; r < 4; ++r) {
      int node = nbase + kg * 4 + r;
      float feat = fmaxf(acc[r] + bias, 0.f);
      float hv = h[(size_t)orow[r] * DD + d];
      hfb[node * DD + d] = bf16r(hv) | (bf16r(feat) << 16);
    }
  }
}

// One wave per dst node. Softmax w/o max-subtraction (|e| bounded).
// Batch-16 predicated gathers: deg<=16 nodes (57%) take ONE load round-trip.
// FINAL: fuse l2-normalize(h2), l2-normalize(h1), h0 copy into the epilogue.
template <bool FINAL>
__global__ void __launch_bounds__(256)
k_edge_t(const unsigned* __restrict__ hfb, const float* __restrict__ h,
         const int* __restrict__ ids, const int* __restrict__ rp,
         const int* __restrict__ ssrc, float* __restrict__ outp, int ostride,
         const float* __restrict__ emb, const int* __restrict__ fids,
         const float* __restrict__ h1) {
  int d = threadIdx.x & 63;
  int node = blockIdx.x * 4 + (threadIdx.x >> 6);
  if (node >= NN) return;
  int beg = rp[node], end = rp[node + 1];
  int hrow = ids ? ids[node] : node;
  float hd = h[(size_t)hrow * DD + d];
  float s[8] = {0.f, 0.f, 0.f, 0.f, 0.f, 0.f, 0.f, 0.f};
  float a[8] = {0.f, 0.f, 0.f, 0.f, 0.f, 0.f, 0.f, 0.f};
  int lim = end - 1;
  for (int p = beg; p < end; p += 16) {
    unsigned v[16];
#pragma unroll
    for (int j = 0; j < 16; ++j) {
      int q = p + j;
      q = (q > lim) ? lim : q;  // clamp -> always-valid load, same-address dup
      v[j] = hfb[ssrc[q] * DD + d];
    }
#pragma unroll
    for (int j = 0; j < 16; ++j) {
      float hv = __uint_as_float(v[j] << 16);
      float fv = __uint_as_float(v[j] & 0xffff0000u);
      float ex = (p + j < end) ? __expf(hv * hd) : 0.f;
      s[j & 7] += ex;
      a[j & 7] = fmaf(fv, ex, a[j & 7]);
    }
  }
  float ss = ((s[0] + s[1]) + (s[2] + s[3])) + ((s[4] + s[5]) + (s[6] + s[7]));
  float aa = ((a[0] + a[1]) + (a[2] + a[3])) + ((a[4] + a[5]) + (a[6] + a[7]));
  float hval = (end > beg) ? aa / ss : 0.f;
  if (!FINAL) {
    outp[(size_t)node * ostride + d] = hval;
  } else {
    float v1 = h1[(size_t)node * DD + d];
    float s1 = v1 * v1, s2 = hval * hval;
#pragma unroll
    for (int off = 32; off > 0; off >>= 1) {
      s1 += __shfl_xor(s1, off, 64);
      s2 += __shfl_xor(s2, off, 64);
    }
    outp[node * 192 + d] = emb[(size_t)fids[node] * DD + d];
    outp[node * 192 + 64 + d] = v1 / fmaxf(sqrtf(s1), 1e-12f);
    outp[node * 192 + 128 + d] = hval / fmaxf(sqrtf(s2), 1e-12f);
  }
}

// -------------------- launch --------------------

extern "C" void kernel_launch(void* const* d_in, const int* in_sizes, int n_in,
                              void* d_out, int out_size, void* d_ws, size_t ws_size,
                              hipStream_t stream) {
  const int* node_ids = (const int*)d_in[0];
  const int* src = (const int*)d_in[1];
  const int* dst = (const int*)d_in[2];
  const float* emb = (const float*)d_in[3];
  const float* W0 = (const float*)d_in[4];
  const float* b0 = (const float*)d_in[5];
  const float* W1 = (const float*)d_in[8];
  const float* b1 = (const float*)d_in[9];
  float* out = (float*)d_out;

  size_t o = 0;
  auto alloc = [&](size_t nbytes) {
    char* p = (char*)d_ws + o;
    o += (nbytes + 255) & ~(size_t)255;
    return (void*)p;
  };
  float* h1 = (float*)alloc((size_t)NN * DD * 4);
  unsigned* hfb = (unsigned*)alloc((size_t)NN * DD * 4);
  int* deg = (int*)alloc((size_t)(NN + 12) * 4);
  int* rp = (int*)alloc((size_t)(NN + 1) * 4);
  int* bsum = (int*)alloc(64 * 4);
  int* ssrc = (int*)alloc((size_t)NE * 4);
  int* pos = (int*)alloc((size_t)NE * 4);
  (void)o; (void)ws_size; (void)in_sizes; (void)n_in; (void)out_size;

  // layer-1 FC (independent of CSR) fused with deg zeroing in its tail blocks
  k_fc_mfma<<<FC_BLOCKS + ZB, 256, 0, stream>>>(emb, node_ids, W0, b0, hfb,
                                                (int4*)deg, N4);
  k_hist<<<(NE / 4 + 255) / 256, 256, 0, stream>>>((const int4*)dst, deg, (int4*)pos);
  int NB = (NN + 1023) / 1024;  // 49
  k_scan1<<<NB, 1024, 0, stream>>>(deg, rp, bsum);
  k_scan3<<<NB, 1024, 0, stream>>>(rp, bsum);
  k_scatter<<<(NE / 4 + 255) / 256, 256, 0, stream>>>(
      (const int4*)src, (const int4*)dst, rp, (const int4*)pos, ssrc);

  // layer 1 aggregation
  k_edge_t<false><<<(NN + 3) / 4, 256, 0, stream>>>(
      hfb, emb, node_ids, rp, ssrc, h1, DD, nullptr, nullptr, nullptr);
  // layer 2 FC
  k_fc_mfma<<<FC_BLOCKS, 256, 0, stream>>>(h1, nullptr, W1, b1, hfb, nullptr, 0);
  // layer 2 aggregation + fused finalize (norm h2, norm h1, copy h0)
  k_edge_t<true><<<(NN + 3) / 4, 256, 0, stream>>>(
      hfb, h1, nullptr, rp, ssrc, out, 0, emb, node_ids, h1);
}

// Round 9
// 161.799 us; speedup vs baseline: 1.1620x; 1.0648x over previous
//
#include <hip/hip_runtime.h>
#include <math.h>

#define NN 50000
#define NE 800000
#define DD 64
#define FC_BLOCKS 782  // ceil(NN/64)
#define N4 12500       // NN/4 ints of deg, zeroed as int4
#define ZB 49          // ceil(N4/256) zero blocks appended to fc1 grid

typedef __attribute__((ext_vector_type(8))) short short8v;
typedef __attribute__((ext_vector_type(4))) float floatx4;

__device__ __forceinline__ unsigned bf16r(float x) {  // round-to-nearest-even bf16
  unsigned u = __float_as_uint(x);
  return (u + 0x7fffu + ((u >> 16) & 1u)) >> 16;
}

// -------------------- kernels --------------------

// histogram dst degrees, 4 edges/thread, capturing per-edge position
__global__ void k_hist(const int4* __restrict__ dst4, int* __restrict__ deg,
                       int4* __restrict__ pos4) {
  int q = blockIdx.x * 256 + threadIdx.x;
  if (q >= NE / 4) return;
  int4 dn = dst4[q];
  int4 p;
  p.x = atomicAdd(&deg[dn.x], 1);
  p.y = atomicAdd(&deg[dn.y], 1);
  p.z = atomicAdd(&deg[dn.z], 1);
  p.w = atomicAdd(&deg[dn.w], 1);
  pos4[q] = p;
}

// block-level exclusive scan (1024 threads): shuffle scan per wave + cross-wave LDS
__global__ void k_scan1(const int* __restrict__ deg, int* __restrict__ rp,
                        int* __restrict__ bsum) {
  __shared__ int woff[16];
  int t = threadIdx.x;
  int i = blockIdx.x * 1024 + t;
  int v = (i < NN) ? deg[i] : 0;
  int lane = t & 63, w = t >> 6;
  int sc = v;  // inclusive scan within wave
#pragma unroll
  for (int off = 1; off < 64; off <<= 1) {
    int x = __shfl_up(sc, off, 64);
    if (lane >= off) sc += x;
  }
  if (lane == 63) woff[w] = sc;
  __syncthreads();
  if (t < 16) {
    int ws = woff[t];
    int s2 = ws;
#pragma unroll
    for (int off = 1; off < 16; off <<= 1) {
      int x = __shfl_up(s2, off, 64);
      if (t >= off) s2 += x;
    }
    woff[t] = s2 - ws;  // exclusive wave offset
    if (t == 15) bsum[blockIdx.x] = s2;  // block total
  }
  __syncthreads();
  if (i < NN) rp[i] = sc - v + woff[w];
}

// add cross-block offset: each block reduces bsum[0..blockIdx) with one wave
__global__ void k_scan3(int* __restrict__ rp, const int* __restrict__ bsum) {
  __shared__ int soff;
  if (threadIdx.x < 64) {
    int v = ((int)threadIdx.x < (int)blockIdx.x) ? bsum[threadIdx.x] : 0;
#pragma unroll
    for (int off = 32; off > 0; off >>= 1) v += __shfl_xor(v, off, 64);
    if (threadIdx.x == 0) soff = v;
  }
  __syncthreads();
  int i = blockIdx.x * 1024 + threadIdx.x;
  if (i < NN) rp[i] += soff;
  if (i == 0) rp[NN] = NE;
}

// atomic-free scatter, 4 edges/thread
__global__ void k_scatter(const int4* __restrict__ src4, const int4* __restrict__ dst4,
                          const int* __restrict__ rp, const int4* __restrict__ pos4,
                          int* __restrict__ ssrc) {
  int q = blockIdx.x * 256 + threadIdx.x;
  if (q >= NE / 4) return;
  int4 s = src4[q], dn = dst4[q], p = pos4[q];
  ssrc[rp[dn.x] + p.x] = s.x;
  ssrc[rp[dn.y] + p.y] = s.y;
  ssrc[rp[dn.z] + p.z] = s.z;
  ssrc[rp[dn.w] + p.w] = s.w;
}

// MFMA FC (+ optional deg-zero blocks appended to the grid for layer 1)
__global__ void __launch_bounds__(256) k_fc_mfma(const float* __restrict__ h,
                                                 const int* __restrict__ ids,
                                                 const float* __restrict__ W,
                                                 const float* __restrict__ b,
                                                 unsigned* __restrict__ hfb,
                                                 int4* __restrict__ zbuf, int n4) {
  if (blockIdx.x >= FC_BLOCKS) {  // zero-deg tail blocks (layer 1 only)
    int i = (blockIdx.x - FC_BLOCKS) * 256 + threadIdx.x;
    if (i < n4) zbuf[i] = make_int4(0, 0, 0, 0);
    return;
  }
  int lane = threadIdx.x & 63;
  int wid = threadIdx.x >> 6;
  int nbase = blockIdx.x * 64 + wid * 16;
  if (nbase >= NN) return;
  int r16 = lane & 15, kg = lane >> 4;

  int rowA = ids ? ids[nbase + r16] : (nbase + r16);
  const float* hrow = h + (size_t)rowA * DD;
  short8v afr[2];
#pragma unroll
  for (int kt = 0; kt < 2; ++kt) {
    int k0 = kt * 32 + kg * 8;
#pragma unroll
    for (int i = 0; i < 8; ++i) afr[kt][i] = (short)bf16r(hrow[k0 + i]);
  }
  int orow[4];
#pragma unroll
  for (int r = 0; r < 4; ++r) {
    int node = nbase + kg * 4 + r;
    orow[r] = ids ? ids[node] : node;
  }
  short8v bfr[4][2];
#pragma unroll
  for (int dt = 0; dt < 4; ++dt) {
    const float* wrow = W + (dt * 16 + r16) * 64;
#pragma unroll
    for (int kt = 0; kt < 2; ++kt) {
      int k0 = kt * 32 + kg * 8;
#pragma unroll
      for (int i = 0; i < 8; ++i) bfr[dt][kt][i] = (short)bf16r(wrow[k0 + i]);
    }
  }
#pragma unroll
  for (int dt = 0; dt < 4; ++dt) {
    floatx4 acc = {0.f, 0.f, 0.f, 0.f};
    acc = __builtin_amdgcn_mfma_f32_16x16x32_bf16(afr[0], bfr[dt][0], acc, 0, 0, 0);
    acc = __builtin_amdgcn_mfma_f32_16x16x32_bf16(afr[1], bfr[dt][1], acc, 0, 0, 0);
    int d = dt * 16 + r16;
    float bias = b[d];
#pragma unroll
    for (int r = 0; r < 4; ++r) {
      int node = nbase + kg * 4 + r;
      float feat = fmaxf(acc[r] + bias, 0.f);
      float hv = h[(size_t)orow[r] * DD + d];
      hfb[node * DD + d] = bf16r(hv) | (bf16r(feat) << 16);
    }
  }
}

// One wave per dst node. Softmax w/o max-subtraction (|e| bounded).
// All wave-uniform values forced to SGPR via readfirstlane -> index math on
// SALU, ssrc loads via SMEM; per-slot VALU = unpack x2, mul, exp, add, fma.
// No predication: clamped duplicate slots are subtracted once at the end.
template <bool FINAL>
__global__ void __launch_bounds__(256)
k_edge_t(const unsigned* __restrict__ hfb, const float* __restrict__ h,
         const int* __restrict__ ids, const int* __restrict__ rp,
         const int* __restrict__ ssrc, float* __restrict__ outp, int ostride,
         const float* __restrict__ emb, const int* __restrict__ fids,
         const float* __restrict__ h1) {
  int d = threadIdx.x & 63;
  int node = __builtin_amdgcn_readfirstlane(blockIdx.x * 4 + (threadIdx.x >> 6));
  int beg = __builtin_amdgcn_readfirstlane(rp[node]);
  int end = __builtin_amdgcn_readfirstlane(rp[node + 1]);
  int hrow = ids ? __builtin_amdgcn_readfirstlane(ids[node]) : node;
  float hd = h[(size_t)hrow * DD + d] * 1.44269504f;  // fold log2e: exp(x)=exp2(x*log2e)
  const unsigned* hfb_d = hfb + d;
  float s[8] = {0.f, 0.f, 0.f, 0.f, 0.f, 0.f, 0.f, 0.f};
  float a[8] = {0.f, 0.f, 0.f, 0.f, 0.f, 0.f, 0.f, 0.f};
  int lim = end - 1;
  for (int p = beg; p < end; p += 8) {
    unsigned v[8];
#pragma unroll
    for (int j = 0; j < 8; ++j) {
      int q = p + j;
      q = (q > lim) ? lim : q;  // SALU clamp; dup slots corrected after loop
      int sq = __builtin_amdgcn_readfirstlane(ssrc[q]);
      v[j] = hfb_d[(size_t)sq * DD];
    }
#pragma unroll
    for (int j = 0; j < 8; ++j) {
      float hv = __uint_as_float(v[j] << 16);
      float fv = __uint_as_float(v[j] & 0xffff0000u);
      float ex = __builtin_amdgcn_exp2f(hv * hd);
      s[j] += ex;
      a[j] = fmaf(fv, ex, a[j]);
    }
  }
  float ss = ((s[0] + s[1]) + (s[2] + s[3])) + ((s[4] + s[5]) + (s[6] + s[7]));
  float aa = ((a[0] + a[1]) + (a[2] + a[3])) + ((a[4] + a[5]) + (a[6] + a[7]));
  int deg = end - beg;
  if (deg > 0) {
    int dups = (8 - (deg & 7)) & 7;
    if (dups) {  // uniform branch
      unsigned vL = hfb_d[(size_t)__builtin_amdgcn_readfirstlane(ssrc[lim]) * DD];
      float hvL = __uint_as_float(vL << 16);
      float fvL = __uint_as_float(vL & 0xffff0000u);
      float exL = __builtin_amdgcn_exp2f(hvL * hd);
      float fd = (float)dups;
      ss = fmaf(-fd, exL, ss);
      aa = fmaf(-fd * fvL, exL, aa);
    }
  }
  float hval = (deg > 0) ? aa / ss : 0.f;
  if (!FINAL) {
    outp[(size_t)node * ostride + d] = hval;
  } else {
    float v1 = h1[(size_t)node * DD + d];
    float s1 = v1 * v1, s2 = hval * hval;
#pragma unroll
    for (int off = 32; off > 0; off >>= 1) {
      s1 += __shfl_xor(s1, off, 64);
      s2 += __shfl_xor(s2, off, 64);
    }
    outp[node * 192 + d] = emb[(size_t)fids[node] * DD + d];
    outp[node * 192 + 64 + d] = v1 / fmaxf(sqrtf(s1), 1e-12f);
    outp[node * 192 + 128 + d] = hval / fmaxf(sqrtf(s2), 1e-12f);
  }
}

// -------------------- launch --------------------

extern "C" void kernel_launch(void* const* d_in, const int* in_sizes, int n_in,
                              void* d_out, int out_size, void* d_ws, size_t ws_size,
                              hipStream_t stream) {
  const int* node_ids = (const int*)d_in[0];
  const int* src = (const int*)d_in[1];
  const int* dst = (const int*)d_in[2];
  const float* emb = (const float*)d_in[3];
  const float* W0 = (const float*)d_in[4];
  const float* b0 = (const float*)d_in[5];
  const float* W1 = (const float*)d_in[8];
  const float* b1 = (const float*)d_in[9];
  float* out = (float*)d_out;

  size_t o = 0;
  auto alloc = [&](size_t nbytes) {
    char* p = (char*)d_ws + o;
    o += (nbytes + 255) & ~(size_t)255;
    return (void*)p;
  };
  float* h1 = (float*)alloc((size_t)NN * DD * 4);
  unsigned* hfb = (unsigned*)alloc((size_t)NN * DD * 4);
  int* deg = (int*)alloc((size_t)(NN + 12) * 4);
  int* rp = (int*)alloc((size_t)(NN + 1) * 4);
  int* bsum = (int*)alloc(64 * 4);
  int* ssrc = (int*)alloc((size_t)NE * 4);
  int* pos = (int*)alloc((size_t)NE * 4);
  (void)o; (void)ws_size; (void)in_sizes; (void)n_in; (void)out_size;

  // layer-1 FC (independent of CSR) fused with deg zeroing in its tail blocks
  k_fc_mfma<<<FC_BLOCKS + ZB, 256, 0, stream>>>(emb, node_ids, W0, b0, hfb,
                                                (int4*)deg, N4);
  k_hist<<<(NE / 4 + 255) / 256, 256, 0, stream>>>((const int4*)dst, deg, (int4*)pos);
  int NB = (NN + 1023) / 1024;  // 49
  k_scan1<<<NB, 1024, 0, stream>>>(deg, rp, bsum);
  k_scan3<<<NB, 1024, 0, stream>>>(rp, bsum);
  k_scatter<<<(NE / 4 + 255) / 256, 256, 0, stream>>>(
      (const int4*)src, (const int4*)dst, rp, (const int4*)pos, ssrc);

  // layer 1 aggregation
  k_edge_t<false><<<(NN + 3) / 4, 256, 0, stream>>>(
      hfb, emb, node_ids, rp, ssrc, h1, DD, nullptr, nullptr, nullptr);
  // layer 2 FC
  k_fc_mfma<<<FC_BLOCKS, 256, 0, stream>>>(h1, nullptr, W1, b1, hfb, nullptr, 0);
  // layer 2 aggregation + fused finalize (norm h2, norm h1, copy h0)
  k_edge_t<true><<<(NN + 3) / 4, 256, 0, stream>>>(
      hfb, h1, nullptr, rp, ssrc, out, 0, emb, node_ids, h1);
}